// Round 14
// baseline (129.928 us; speedup 1.0000x reference)
//
#include <hip/hip_runtime.h>
#include <cstddef>

namespace {

typedef float f2 __attribute__((ext_vector_type(2)));
typedef float f4v __attribute__((ext_vector_type(4)));

constexpr int IMG = 256;
constexpr long long N_ELEM = 16LL * 8 * IMG * IMG;   // 8388608

constexpr int NTHR   = 1024;           // 16 waves = 16 row-teams (STRIP 6)
constexpr int DSTR   = 256;            // boundary row stride = full width
constexpr int DSLOTS = 32;             // 2 slots per wave (row0, row5)
constexpr int DBUF   = DSLOTS * DSTR;  // 8192 floats = 32 KB per buffer

constexpr float RP   = 3.9f;
constexpr float BET  = 0.15f;
constexpr float IBET = 1.0f / 0.15f;
constexpr float KF   = 0.255f;         // 0.85 * 0.3
constexpr float CF   = 0.595f;         // 0.85 * 0.7
constexpr float CLO  = 1e-4f;
constexpr float CHI  = (float)(1.0 - 1e-4);

__device__ __forceinline__ f2 mkf2(float a, float b) { f2 r; r.x = a; r.y = b; return r; }
__device__ __forceinline__ f2 sp(float v) { return mkf2(v, v); }
#define FMA2(A, B, C) __builtin_elementwise_fma((A), (B), (C))

__device__ __forceinline__ float dpp_up(float x) {   // lane i <- i-1, lane0 <- 0
    return __int_as_float(__builtin_amdgcn_update_dpp(
        0, __float_as_int(x), 0x138, 0xf, 0xf, true));
}
__device__ __forceinline__ float dpp_dn(float x) {   // lane i <- i+1, lane63 <- 0
    return __int_as_float(__builtin_amdgcn_update_dpp(
        0, __float_as_int(x), 0x130, 0xf, 0xf, true));
}

__device__ __forceinline__ f2 mapfp(f2 g) {          // 3.9*g*(1-g), fused (pk)
    f2 t = sp(RP) * g;
    return FMA2(-t, g, t);
}

// packed px9: identical per-component op order to the scalar version
__device__ __forceinline__ f2 px9p(const float* k2,
        f2 a0, f2 a1, f2 a2, f2 b0, f2 b1, f2 b2,
        f2 c0, f2 c1, f2 c2, f2 bdv) {
    f2 a = bdv;
    a = FMA2(sp(k2[0]), a0, a); a = FMA2(sp(k2[1]), a1, a); a = FMA2(sp(k2[2]), a2, a);
    a = FMA2(sp(k2[3]), b0, a); a = FMA2(sp(k2[4]), b1, a); a = FMA2(sp(k2[5]), b2, a);
    a = FMA2(sp(k2[6]), c0, a); a = FMA2(sp(k2[7]), c1, a); a = FMA2(sp(k2[8]), c2, a);
    a = FMA2(sp(CF), b1, a);
    f2 r; r.x = __builtin_amdgcn_fmed3f(a.x, CLO, CHI);
    r.y = __builtin_amdgcn_fmed3f(a.y, CLO, CHI);
    return r;
}

// build the 5 operand-pairs of a row window from its 2 state pairs.
// Wm1=(m[c-1],m[c0]) W0=(m0,m1) W1=(m1,m2) W2=(m2,m3) W3=(m3,m[c+4])
#define SETWIN(W, Pa, Pb) {                          \
    float ml_ = dpp_up((Pb).y);                      \
    float mr_ = dpp_dn((Pa).x);                      \
    W##m1 = mkf2(ml_, (Pa).x);                       \
    W##0  = (Pa);                                    \
    W##1  = mkf2((Pa).y, (Pb).x);                    \
    W##2  = (Pb);                                    \
    W##3  = mkf2((Pb).y, mr_); }

// one output row I from window sets A(r-1), B(r), C(r+1)
#define ROWP(A, B, C, I, OWN, F) {                                               \
    f2 g0_ = px9p(k2, A##m1, A##0, A##1, B##m1, B##0, B##1,                      \
                      C##m1, C##0, C##1, bdv##I##a);                             \
    f2 g1_ = px9p(k2, A##1, A##2, A##3, B##1, B##2, B##3,                        \
                      C##1, C##2, C##3, bdv##I##b);                              \
    if (OWN) {                                                                   \
        sum##I##a += g0_; sum##I##b += g1_;                                      \
        sq##I##a = FMA2(g0_, g0_, sq##I##a);                                     \
        sq##I##b = FMA2(g1_, g1_, sq##I##b);                                     \
    }                                                                            \
    if (F) { stg##I##a = g0_; stg##I##b = g1_; }                                 \
    else   { stg##I##a = mapfp(g0_); stg##I##b = mapfp(g1_); } }

// one timestep: 2 boundary reads, 6 rows in regs, 2 boundary writes.
#define STEPP(F, DR, DW) {                                                      \
    f2 qLa, qLb, qRa, qRb;                                                      \
    if (wv > 0) {                                                               \
        f4v q = *(const f4v*)((DR) + (2*wv - 1) * DSTR + c4);                   \
        qLa = mkf2(q.x, q.y); qLb = mkf2(q.z, q.w);                             \
    } else { qLa = mkf2(0.f, 0.f); qLb = qLa; }                                 \
    if (wv < 15) {                                                              \
        f4v q = *(const f4v*)((DR) + (2*wv + 2) * DSTR + c4);                   \
        qRa = mkf2(q.x, q.y); qRb = mkf2(q.z, q.w);                             \
    } else { qRa = mkf2(0.f, 0.f); qRb = qRa; }                                 \
    f2 wAm1, wA0, wA1, wA2, wA3;                                                \
    f2 wBm1, wB0, wB1, wB2, wB3;                                                \
    f2 wCm1, wC0, wC1, wC2, wC3;                                                \
    SETWIN(wA, qLa, qLb)                                                        \
    SETWIN(wB, stg0a, stg0b)                                                    \
    SETWIN(wC, stg1a, stg1b)                                                    \
    ROWP(wA, wB, wC, 0, ow0, F)                                                 \
    SETWIN(wA, stg2a, stg2b)                                                    \
    ROWP(wB, wC, wA, 1, ow1, F)                                                 \
    SETWIN(wB, stg3a, stg3b)                                                    \
    ROWP(wC, wA, wB, 2, ow2, F)                                                 \
    SETWIN(wC, stg4a, stg4b)                                                    \
    ROWP(wA, wB, wC, 3, ow3, F)                                                 \
    SETWIN(wA, stg5a, stg5b)                                                    \
    ROWP(wB, wC, wA, 4, ow4, F)                                                 \
    SETWIN(wB, qRa, qRb)                                                        \
    ROWP(wC, wA, wB, 5, ow5, F)                                                 \
    if (!(F)) {                                                                 \
        *(f4v*)((DW) + (2*wv    ) * DSTR + c4) =                                \
            __builtin_shufflevector(stg0a, stg0b, 0, 1, 2, 3);                  \
        *(f4v*)((DW) + (2*wv + 1) * DSTR + c4) =                                \
            __builtin_shufflevector(stg5a, stg5b, 0, 1, 2, 3);                  \
    } }

#define DECLROW(I) f2 stg##I##a, stg##I##b, bdv##I##a, bdv##I##b,               \
                      sum##I##a, sum##I##b, sq##I##a, sq##I##b;

#define INITROW(I) {                                                             \
    const int y = y0 + 6 * wv + (I);                                             \
    f4v t = *(const f4v*)(dimg + y * IMG + c4);                                  \
    f2 lo = mkf2(t.x, t.y), hi = mkf2(t.z, t.w);                                 \
    stg##I##a = mapfp(lo); stg##I##b = mapfp(hi);                                \
    bdv##I##a = sp(BET) * lo; bdv##I##b = sp(BET) * hi;                          \
    sum##I##a = mkf2(0.f, 0.f); sum##I##b = sum##I##a;                           \
    sq##I##a = sum##I##a; sq##I##b = sum##I##a; }

#define EPIROW(I) {                                                              \
    const int r = 6 * wv + (I);                                                  \
    if (r >= os && r <= oe) {                                                    \
        const int y = y0 + r;                                                    \
        size_t base = (size_t)img * (IMG*IMG) + (size_t)y * IMG + c4;            \
        f2 mna = sum##I##a * sp(inv15), mnb = sum##I##b * sp(inv15);             \
        f2 va = FMA2(-mna, mna, sq##I##a * sp(inv15));                           \
        f2 vb = FMA2(-mnb, mnb, sq##I##b * sp(inv15));                           \
        va.x = fmaxf(va.x, 0.f); va.y = fmaxf(va.y, 0.f);                        \
        vb.x = fmaxf(vb.x, 0.f); vb.y = fmaxf(vb.y, 0.f);                        \
        f2 da = FMA2(-bdv##I##a, sp(IBET), stg##I##a);                           \
        f2 db = FMA2(-bdv##I##b, sp(IBET), stg##I##b);                           \
        f4v g4 = __builtin_shufflevector(stg##I##a, stg##I##b, 0, 1, 2, 3);      \
        f4v m4 = __builtin_shufflevector(mna, mnb, 0, 1, 2, 3);                  \
        f4v v4 = __builtin_shufflevector(va, vb, 0, 1, 2, 3);                    \
        f4v d4 = __builtin_shufflevector(da, db, 0, 1, 2, 3);                    \
        *(f4v*)(out + 0*N_ELEM + base) = g4;                                     \
        *(f4v*)(out + 1*N_ELEM + base) = m4;                                     \
        *(f4v*)(out + 2*N_ELEM + base) = v4;                                     \
        *(f4v*)(out + 3*N_ELEM + base) = d4;                                     \
        *(f4v*)(out + 4*N_ELEM + base) = d4; } }

__global__ __launch_bounds__(NTHR, 4)   // 16-wave WG -> 4 waves/EU, 128-reg cap
void cml_kernel(const float* __restrict__ drive,
                const float* __restrict__ Kl,
                float* __restrict__ out)
{
    __shared__ __align__(16) float lds[2 * DBUF];   // 65536 B
    float* Da = lds;
    float* Db = lds + DBUF;

    const int bx   = blockIdx.x;
    const int img  = bx >> 2;              // 0..127  (b*8 + c)
    const int band = bx & 3;               // 4 bands x 96 in-image rows
    const int y0 = (band == 0) ? 0 : (band == 3) ? 160 : (band == 1) ? 48 : 112;
    const int os = (band == 0) ? 0 : (band == 3) ? 32 : 16;   // band-rel outputs
    const int oe = os + 63;

    const int tid  = threadIdx.x;
    const int lane = tid & 63;
    const int wv   = tid >> 6;             // 0..15
    const int c4   = lane * 4;

    // cone-of-influence deadline (validated: reproduces R13 lims for all bands)
    const int lim = min(15, min(6 * wv + 20 - os, oe + 15 - 6 * wv));

    // row ownership (wave-uniform)
    const bool ow0 = (6*wv+0 >= os) && (6*wv+0 <= oe);
    const bool ow1 = (6*wv+1 >= os) && (6*wv+1 <= oe);
    const bool ow2 = (6*wv+2 >= os) && (6*wv+2 <= oe);
    const bool ow3 = (6*wv+3 >= os) && (6*wv+3 <= oe);
    const bool ow4 = (6*wv+4 >= os) && (6*wv+4 <= oe);
    const bool ow5 = (6*wv+5 >= os) && (6*wv+5 <= oe);

    const int ch = img & 7;
    float k2[9];
#pragma unroll
    for (int i = 0; i < 9; ++i)            // uniform -> SGPR (VOP3P takes 1 SGPR)
        k2[i] = __int_as_float(__builtin_amdgcn_readfirstlane(
                    __float_as_int(KF * Kl[ch * 9 + i])));

    const float* dimg = drive + (size_t)img * (IMG * IMG);

    DECLROW(0) DECLROW(1) DECLROW(2) DECLROW(3) DECLROW(4) DECLROW(5)
    INITROW(0) INITROW(1) INITROW(2) INITROW(3) INITROW(4) INITROW(5)

    *(f4v*)(Da + (2*wv    ) * DSTR + c4) = __builtin_shufflevector(stg0a, stg0b, 0,1,2,3);
    *(f4v*)(Da + (2*wv + 1) * DSTR + c4) = __builtin_shufflevector(stg5a, stg5b, 0,1,2,3);
    __syncthreads();

    // ---- steps 0..13 (ping-pong, one barrier each; skip compute past lim)
#pragma unroll 1
    for (int s2 = 0; s2 < 7; ++s2) {
        if (2 * s2 < lim)     { STEPP(0, Da, Db) }
        __syncthreads();
        if (2 * s2 + 1 < lim) { STEPP(0, Db, Da) }
        __syncthreads();
    }
    // final step t=14 (reads state-14 boundaries in Da): output waves only
    if (lim >= 15) { STEPP(1, Da, Db) }

    // ---- epilogue
    const float inv15 = 1.0f / 15.0f;
    EPIROW(0) EPIROW(1) EPIROW(2) EPIROW(3) EPIROW(4) EPIROW(5)
}

} // namespace

extern "C" void kernel_launch(void* const* d_in, const int* in_sizes, int n_in,
                              void* d_out, int out_size, void* d_ws, size_t ws_size,
                              hipStream_t stream) {
    const float* drive = (const float*)d_in[0];
    const float* Kl    = (const float*)d_in[1];
    float* out         = (float*)d_out;
    (void)in_sizes; (void)n_in; (void)out_size; (void)d_ws; (void)ws_size;

    dim3 grid(128 * 4);   // 128 images * 4 bands
    dim3 block(NTHR);
    cml_kernel<<<grid, block, 0, stream>>>(drive, Kl, out);
}

// Round 15
// 96.901 us; speedup vs baseline: 1.3408x; 1.3408x over previous
//
#include <hip/hip_runtime.h>
#include <cstddef>

namespace {

constexpr int IMG = 256;
constexpr long long N_ELEM = 16LL * 8 * IMG * IMG;   // 8388608

constexpr int NTHR   = 1024;           // 16 waves = 16 row-teams
constexpr int DSTR   = 256;            // boundary row stride = full width
constexpr int DSLOTS = 32;             // 2 slots per wave (r_first, r_last)
constexpr int DBUF   = DSLOTS * DSTR;  // 8192 floats = 32 KB per buffer

constexpr float RP   = 3.9f;
constexpr float BET  = 0.15f;
constexpr float IBET = 1.0f / 0.15f;
constexpr float KF   = 0.255f;         // 0.85 * 0.3  (folded conv coefficient)
constexpr float CF   = 0.595f;         // 0.85 * 0.7  (folded center coefficient)
constexpr float CLO  = 1e-4f;
constexpr float CHI  = (float)(1.0 - 1e-4);

__device__ __forceinline__ float mapf(float g) {
    float t = RP * g;
    return fmaf(-t, g, t);             // 3.9*g*(1-g), fused
}

// DPP wave-wide shifts: pure VALU, 0-fill at wave edge (= real image zero-pad).
__device__ __forceinline__ float dpp_up(float x) {
    return __int_as_float(__builtin_amdgcn_update_dpp(
        0, __float_as_int(x), 0x138, 0xf, 0xf, true));
}
__device__ __forceinline__ float dpp_dn(float x) {
    return __int_as_float(__builtin_amdgcn_update_dpp(
        0, __float_as_int(x), 0x130, 0xf, 0xf, true));
}

// folded update: g = med3(bdv + sum k2_i*m_i + 0.595*m_center, CLO, CHI)
// (inputs finite -> med3 == clamp, bit-exact, 1 instruction)
__device__ __forceinline__ float px9(const float k2[9],
        float a0, float a1, float a2, float b0, float b1, float b2,
        float c0, float c1, float c2, float bdv) {
    float a = bdv;
    a = fmaf(k2[0], a0, a); a = fmaf(k2[1], a1, a); a = fmaf(k2[2], a2, a);
    a = fmaf(k2[3], b0, a); a = fmaf(k2[4], b1, a); a = fmaf(k2[5], b2, a);
    a = fmaf(k2[6], c0, a); a = fmaf(k2[7], c1, a); a = fmaf(k2[8], c2, a);
    a = fmaf(CF, b1, a);
    return __builtin_amdgcn_fmed3f(a, CLO, CHI);
}

// 6-wide window from a full-width row quad: halos via DPP wave shifts.
#define WINQ(W, QX, QY, QZ, QW) {                       \
    W[1] = (QX); W[2] = (QY); W[3] = (QZ); W[4] = (QW); \
    W[0] = dpp_up(QW);                                  \
    W[5] = dpp_dn(QX);                                  \
}

// one output row from windows WA(r-1), WB(r), WC(r+1); stats (gated by OWN,
// wave-uniform) + STG in place.
#define ROWB(WA, WB, WC, BDV, SUM, SQ, STG, OWN, F) {                                      \
    float g0 = px9(k2, WA[0],WA[1],WA[2], WB[0],WB[1],WB[2], WC[0],WC[1],WC[2], BDV.x);    \
    float g1 = px9(k2, WA[1],WA[2],WA[3], WB[1],WB[2],WB[3], WC[1],WC[2],WC[3], BDV.y);    \
    float g2 = px9(k2, WA[2],WA[3],WA[4], WB[2],WB[3],WB[4], WC[2],WC[3],WC[4], BDV.z);    \
    float g3 = px9(k2, WA[3],WA[4],WA[5], WB[3],WB[4],WB[5], WC[3],WC[4],WC[5], BDV.w);    \
    if (OWN) {                                                                             \
        SUM.x += g0; SUM.y += g1; SUM.z += g2; SUM.w += g3;                                \
        SQ.x = fmaf(g0,g0,SQ.x); SQ.y = fmaf(g1,g1,SQ.y);                                  \
        SQ.z = fmaf(g2,g2,SQ.z); SQ.w = fmaf(g3,g3,SQ.w);                                  \
    }                                                                                      \
    if (F) { STG.x = g0; STG.y = g1; STG.z = g2; STG.w = g3; }                             \
    else   { STG.x = mapf(g0); STG.y = mapf(g1); STG.z = mapf(g2); STG.w = mapf(g3); }     \
}

// boundary reads: wave w reads (w-1).r_last at slot 2w-1, (w+1).r_first at 2w+2
#define QLOAD(DR) \
    float4 qL, qR;                                                              \
    if (wv > 0)  qL = *(const float4*)((DR) + (2*wv - 1) * DSTR + c4);          \
    else { qL.x = 0.f; qL.y = 0.f; qL.z = 0.f; qL.w = 0.f; }                    \
    if (wv < 15) qR = *(const float4*)((DR) + (2*wv + 2) * DSTR + c4);          \
    else { qR.x = 0.f; qR.y = 0.f; qR.z = 0.f; qR.w = 0.f; }

// one timestep, STRIP=6 (interior): rows r0..r5 in regs, 2 boundary rows via LDS
#define STEP6(F, DR, DW) {                                                      \
    QLOAD(DR)                                                                   \
    float wA[6], wB[6], wC[6];                                                  \
    WINQ(wA, qL.x, qL.y, qL.z, qL.w)                                            \
    WINQ(wB, stg0.x, stg0.y, stg0.z, stg0.w)                                    \
    WINQ(wC, stg1.x, stg1.y, stg1.z, stg1.w)                                    \
    ROWB(wA, wB, wC, bdv0, sum0, sq0, stg0, ow0, F)                             \
    WINQ(wA, stg2.x, stg2.y, stg2.z, stg2.w)                                    \
    ROWB(wB, wC, wA, bdv1, sum1, sq1, stg1, ow1, F)                             \
    WINQ(wB, stg3.x, stg3.y, stg3.z, stg3.w)                                    \
    ROWB(wC, wA, wB, bdv2, sum2, sq2, stg2, ow2, F)                             \
    WINQ(wC, stg4.x, stg4.y, stg4.z, stg4.w)                                    \
    ROWB(wA, wB, wC, bdv3, sum3, sq3, stg3, ow3, F)                             \
    WINQ(wA, stg5.x, stg5.y, stg5.z, stg5.w)                                    \
    ROWB(wB, wC, wA, bdv4, sum4, sq4, stg4, ow4, F)                             \
    WINQ(wB, qR.x, qR.y, qR.z, qR.w)                                            \
    ROWB(wC, wA, wB, bdv5, sum5, sq5, stg5, ow5, F)                             \
    if (!(F)) {                                                                 \
        *(float4*)((DW) + (2*wv    ) * DSTR + c4) = stg0;                       \
        *(float4*)((DW) + (2*wv + 1) * DSTR + c4) = stg5;                       \
    }                                                                           \
}

// one timestep, STRIP=5 (edge bands)
#define STEP5(F, DR, DW) {                                                      \
    QLOAD(DR)                                                                   \
    float wA[6], wB[6], wC[6];                                                  \
    WINQ(wA, qL.x, qL.y, qL.z, qL.w)                                            \
    WINQ(wB, stg0.x, stg0.y, stg0.z, stg0.w)                                    \
    WINQ(wC, stg1.x, stg1.y, stg1.z, stg1.w)                                    \
    ROWB(wA, wB, wC, bdv0, sum0, sq0, stg0, ow0, F)                             \
    WINQ(wA, stg2.x, stg2.y, stg2.z, stg2.w)                                    \
    ROWB(wB, wC, wA, bdv1, sum1, sq1, stg1, ow1, F)                             \
    WINQ(wB, stg3.x, stg3.y, stg3.z, stg3.w)                                    \
    ROWB(wC, wA, wB, bdv2, sum2, sq2, stg2, ow2, F)                             \
    WINQ(wC, stg4.x, stg4.y, stg4.z, stg4.w)                                    \
    ROWB(wA, wB, wC, bdv3, sum3, sq3, stg3, ow3, F)                             \
    WINQ(wA, qR.x, qR.y, qR.z, qR.w)                                            \
    ROWB(wB, wC, wA, bdv4, sum4, sq4, stg4, ow4, F)                             \
    if (!(F)) {                                                                 \
        *(float4*)((DW) + (2*wv    ) * DSTR + c4) = stg0;                       \
        *(float4*)((DW) + (2*wv + 1) * DSTR + c4) = stg4;                       \
    }                                                                           \
}

#define INITROW(I, STRIDE) {                                                     \
    const int y = y0 + STRIDE * wv + (I);                                        \
    float4 t = *(const float4*)(dimg + y * IMG + c4);                            \
    stg##I.x = mapf(t.x); stg##I.y = mapf(t.y);                                  \
    stg##I.z = mapf(t.z); stg##I.w = mapf(t.w);                                  \
    bdv##I.x = BET * t.x; bdv##I.y = BET * t.y;                                  \
    bdv##I.z = BET * t.z; bdv##I.w = BET * t.w;                                  \
    sum##I.x = 0.f; sum##I.y = 0.f; sum##I.z = 0.f; sum##I.w = 0.f;              \
    sq##I = sum##I; }

#define EPISTORE(I) {                                                             \
    size_t base = (size_t)img * (IMG*IMG) + (size_t)y * IMG + c4;                 \
    float mn0 = sum##I.x*inv15, mn1 = sum##I.y*inv15;                             \
    float mn2 = sum##I.z*inv15, mn3 = sum##I.w*inv15;                             \
    float4 m4; m4.x=mn0; m4.y=mn1; m4.z=mn2; m4.w=mn3;                            \
    float4 v4;                                                                    \
    v4.x = fmaxf(fmaf(-mn0, mn0, sq##I.x*inv15), 0.f);                            \
    v4.y = fmaxf(fmaf(-mn1, mn1, sq##I.y*inv15), 0.f);                            \
    v4.z = fmaxf(fmaf(-mn2, mn2, sq##I.z*inv15), 0.f);                            \
    v4.w = fmaxf(fmaf(-mn3, mn3, sq##I.w*inv15), 0.f);                            \
    float4 d4;                                                                    \
    d4.x = fmaf(-bdv##I.x, IBET, stg##I.x); d4.y = fmaf(-bdv##I.y, IBET, stg##I.y);\
    d4.z = fmaf(-bdv##I.z, IBET, stg##I.z); d4.w = fmaf(-bdv##I.w, IBET, stg##I.w);\
    *(float4*)(out + 0*N_ELEM + base) = stg##I;                                   \
    *(float4*)(out + 1*N_ELEM + base) = m4;                                       \
    *(float4*)(out + 2*N_ELEM + base) = v4;                                       \
    *(float4*)(out + 3*N_ELEM + base) = d4;                                       \
    *(float4*)(out + 4*N_ELEM + base) = d4; }

// ---------------- interior bands (ty=1,2): 96 rows, STRIP=6 ----------------
__device__ __forceinline__ void run_int(const float* __restrict__ drive,
                                        const float* __restrict__ Kl,
                                        float* __restrict__ out,
                                        int img, int ty, float* __restrict__ lds)
{
    float* Da = lds;
    float* Db = lds + DBUF;
    const int tid  = threadIdx.x;
    const int lane = tid & 63;
    const int wv   = tid >> 6;                 // 0..15
    const int c4   = lane * 4;

    // cone deadlines: top lim = 6w+4, bottom lim = 6(15-w)+4, cap 15
    const int lt = 6 * wv + 4;
    const int lb = 6 * (15 - wv) + 4;
    const int lim = min(15, min(lt, lb));

    // stats ownership (wave-uniform): band-rel output rows are [16,79]
    const bool ow0 = (6*wv+0 >= 16) && (6*wv+0 <= 79);
    const bool ow1 = (6*wv+1 >= 16) && (6*wv+1 <= 79);
    const bool ow2 = (6*wv+2 >= 16) && (6*wv+2 <= 79);
    const bool ow3 = (6*wv+3 >= 16) && (6*wv+3 <= 79);
    const bool ow4 = (6*wv+4 >= 16) && (6*wv+4 <= 79);
    const bool ow5 = (6*wv+5 >= 16) && (6*wv+5 <= 79);

    const int ch = img & 7;
    float k2[9];
#pragma unroll
    for (int i = 0; i < 9; ++i) k2[i] = KF * Kl[ch * 9 + i];

    const float* dimg = drive + (size_t)img * (IMG * IMG);
    const int y0 = ty * 64 - 16;               // 48 or 112; all rows in-image

    float4 bdv0,bdv1,bdv2,bdv3,bdv4,bdv5;
    float4 stg0,stg1,stg2,stg3,stg4,stg5;
    float4 sum0,sum1,sum2,sum3,sum4,sum5;
    float4 sq0,sq1,sq2,sq3,sq4,sq5;

    INITROW(0,6) INITROW(1,6) INITROW(2,6) INITROW(3,6) INITROW(4,6) INITROW(5,6)

    *(float4*)(Da + (2*wv    ) * DSTR + c4) = stg0;
    *(float4*)(Da + (2*wv + 1) * DSTR + c4) = stg5;
    __syncthreads();

#pragma unroll 1
    for (int s2 = 0; s2 < 7; ++s2) {
        if (2 * s2 < lim)     { STEP6(0, Da, Db) }
        __syncthreads();
        if (2 * s2 + 1 < lim) { STEP6(0, Db, Da) }
        __syncthreads();
    }
    if (lim >= 15) { STEP6(1, Da, Db) }        // final step reads state-14 (in Da)

    if (wv >= 2 && wv <= 13) {
        const float inv15 = 1.0f / 15.0f;
#define EPI6(I) { const int r = 6*wv + (I);                                       \
        if (r >= 16 && r <= 79) { const int y = y0 + r; EPISTORE(I) } }
        EPI6(0) EPI6(1) EPI6(2) EPI6(3) EPI6(4) EPI6(5)
#undef EPI6
    }
}

// ---------------- edge bands (ty=0 TOP / ty=3 BOT): 80 rows, STRIP=5 --------
template<bool TOP>
__device__ __forceinline__ void run_edge(const float* __restrict__ drive,
                                         const float* __restrict__ Kl,
                                         float* __restrict__ out,
                                         int img, float* __restrict__ lds)
{
    float* Da = lds;
    float* Db = lds + DBUF;
    const int tid  = threadIdx.x;
    const int lane = tid & 63;
    const int wv   = tid >> 6;
    const int c4   = lane * 4;

    // TOP: real zero-pad at top, erosion from bottom -> lim = 78-5w
    // BOT: real zero-pad at bottom, erosion from top -> lim = 3+5w
    const int lim = TOP ? min(15, 78 - 5 * wv) : min(15, 3 + 5 * wv);

    // stats ownership: TOP outputs band-rel rows <=63, BOT rows >=16
    const bool ow0 = TOP ? (5*wv+0 <= 63) : (5*wv+0 >= 16);
    const bool ow1 = TOP ? (5*wv+1 <= 63) : (5*wv+1 >= 16);
    const bool ow2 = TOP ? (5*wv+2 <= 63) : (5*wv+2 >= 16);
    const bool ow3 = TOP ? (5*wv+3 <= 63) : (5*wv+3 >= 16);
    const bool ow4 = TOP ? (5*wv+4 <= 63) : (5*wv+4 >= 16);

    const int ch = img & 7;
    float k2[9];
#pragma unroll
    for (int i = 0; i < 9; ++i) k2[i] = KF * Kl[ch * 9 + i];

    const float* dimg = drive + (size_t)img * (IMG * IMG);
    const int y0 = TOP ? 0 : 176;              // rows 0..79 / 176..255, in-image

    float4 bdv0,bdv1,bdv2,bdv3,bdv4;
    float4 stg0,stg1,stg2,stg3,stg4;
    float4 sum0,sum1,sum2,sum3,sum4;
    float4 sq0,sq1,sq2,sq3,sq4;

    INITROW(0,5) INITROW(1,5) INITROW(2,5) INITROW(3,5) INITROW(4,5)

    *(float4*)(Da + (2*wv    ) * DSTR + c4) = stg0;
    *(float4*)(Da + (2*wv + 1) * DSTR + c4) = stg4;
    __syncthreads();

#pragma unroll 1
    for (int s2 = 0; s2 < 7; ++s2) {
        if (2 * s2 < lim)     { STEP5(0, Da, Db) }
        __syncthreads();
        if (2 * s2 + 1 < lim) { STEP5(0, Db, Da) }
        __syncthreads();
    }
    if (lim >= 15) { STEP5(1, Da, Db) }

    const bool own = TOP ? (wv <= 12) : (wv >= 3);
    if (own) {
        const float inv15 = 1.0f / 15.0f;
#define EPI5(I) { const int r = 5*wv + (I);                                       \
        if (TOP ? (r <= 63) : (r >= 16)) { const int y = y0 + r; EPISTORE(I) } }
        EPI5(0) EPI5(1) EPI5(2) EPI5(3) EPI5(4)
#undef EPI5
    }
}

__global__ __launch_bounds__(NTHR, 4)   // 16-wave WG = 4 waves/EU
void cml_kernel(const float* __restrict__ drive,
                const float* __restrict__ Kl,
                float* __restrict__ out)
{
    __shared__ __align__(16) float lds[2 * DBUF];   // 65536 B exactly
    const int bx  = blockIdx.x;
    const int img = bx >> 2;         // 0..127  (b*8 + c)
    const int t   = bx & 3;          // band
    if      (t == 0) run_edge<true >(drive, Kl, out, img, lds);
    else if (t == 3) run_edge<false>(drive, Kl, out, img, lds);
    else             run_int(drive, Kl, out, img, t, lds);
}

} // namespace

extern "C" void kernel_launch(void* const* d_in, const int* in_sizes, int n_in,
                              void* d_out, int out_size, void* d_ws, size_t ws_size,
                              hipStream_t stream) {
    const float* drive = (const float*)d_in[0];
    const float* Kl    = (const float*)d_in[1];
    float* out         = (float*)d_out;
    (void)in_sizes; (void)n_in; (void)out_size; (void)d_ws; (void)ws_size;

    dim3 grid(128 * 4);   // 128 images * 4 bands
    dim3 block(NTHR);
    cml_kernel<<<grid, block, 0, stream>>>(drive, Kl, out);
}